// Round 2
// baseline (410.863 us; speedup 1.0000x reference)
//
#include <hip/hip_runtime.h>
#include <math.h>

#define C_DIM 256
#define HWDIM 256
#define PATCH_SZ 8
#define R_DIM 32          // C / r
#define PS_PITCH 17       // padded pitch for per-channel partial sums

// Per block: one 8x8 patch, 256 channels. 256 threads.
// Thread t owns: pixel group pg = t&15 (4 consecutive pixels: h=(t>>1)&7, half=t&1),
//                channels c = it*16 + (t>>4), it = 0..15  -> 16 float4 held in VGPRs.
__global__ __launch_bounds__(256, 4)
void lpa_fused_kernel(const float* __restrict__ x,
                      const float* __restrict__ gamma,
                      const float* __restrict__ beta,
                      const float* __restrict__ w1,
                      const float* __restrict__ w2,
                      float* __restrict__ out,
                      int nwg)
{
    __shared__ float sp[16 * 16 * 4];        // [cg][pg][j] per-pixel partial sums
    __shared__ float sq[16 * 16 * 4];        // [cg][pg][j] per-pixel partial sumsq
    __shared__ float ps[C_DIM * PS_PITCH];   // [c][pg] per-channel partials (padded)
    __shared__ float mu_s[64];
    __shared__ float rs_s[64];
    __shared__ float pm_s[C_DIM];
    __shared__ float h_s[R_DIM];
    __shared__ float A_s[C_DIM];             // gamma[c] * gate[c]
    __shared__ float B_s[C_DIM];             // beta[c]  * gate[c]

    const int t = threadIdx.x;
    const int bid = blockIdx.x;

    // XCD-aware bijective swizzle (nwg is a multiple of 8): consecutive patches
    // (which share 128B cache lines along W) stay on one XCD's L2.
    const int per_xcd = nwg >> 3;
    const int pid = (bid & 7) * per_xcd + (bid >> 3);

    const int b  = pid >> 10;                // 1024 patches per image
    const int ij = pid & 1023;
    const unsigned H0 = (unsigned)(ij >> 5) * PATCH_SZ;
    const unsigned W0 = (unsigned)(ij & 31) * PATCH_SZ;
    const unsigned baseb = (unsigned)b * (C_DIM * HWDIM * HWDIM);

    const unsigned hh   = ((unsigned)t >> 1) & 7;   // pixel row in patch
    const unsigned half = (unsigned)t & 1;          // which float4 of the row
    const unsigned cg   = (unsigned)t >> 4;         // channel offset in group of 16
    const unsigned pg   = (unsigned)t & 15;         // pixel group id (4 px each)
    const unsigned p0   = hh * 8 + half * 4;        // first pixel index (0..63)

    const unsigned rowoff = baseb + (H0 + hh) * HWDIM + W0 + half * 4u;

    // ---- Stage 1: load 16 float4 into registers + per-pixel partial stats ----
    float4 v[16];
    float s0 = 0.f, s1 = 0.f, s2 = 0.f, s3 = 0.f;
    float q0 = 0.f, q1 = 0.f, q2 = 0.f, q3 = 0.f;
#pragma unroll
    for (int it = 0; it < 16; ++it) {
        unsigned c = (unsigned)it * 16u + cg;
        v[it] = *reinterpret_cast<const float4*>(x + rowoff + c * (HWDIM * HWDIM));
        s0 += v[it].x; q0 += v[it].x * v[it].x;
        s1 += v[it].y; q1 += v[it].y * v[it].y;
        s2 += v[it].z; q2 += v[it].z * v[it].z;
        s3 += v[it].w; q3 += v[it].w * v[it].w;
    }
    *reinterpret_cast<float4*>(&sp[(cg * 16 + pg) * 4]) = make_float4(s0, s1, s2, s3);
    *reinterpret_cast<float4*>(&sq[(cg * 16 + pg) * 4]) = make_float4(q0, q1, q2, q3);

    // gamma/beta for channel t (used when this thread acts as channel t)
    float g_c = gamma[t];
    float b_c = beta[t];
    __syncthreads();

    // ---- Stage 2: finalize per-pixel LN stats (64 threads, one per pixel) ----
    if (t < 64) {
        const int pgi = t >> 2;
        const int j   = t & 3;
        float s = 0.f, q = 0.f;
#pragma unroll
        for (int k = 0; k < 16; ++k) {
            s += sp[(k * 16 + pgi) * 4 + j];
            q += sq[(k * 16 + pgi) * 4 + j];
        }
        float mu  = s * (1.0f / 256.0f);
        float var = q * (1.0f / 256.0f) - mu * mu;
        mu_s[t] = mu;
        rs_s[t] = rsqrtf(var + 1e-5f);
    }
    __syncthreads();

    // ---- Stage 3a: per-channel weighted sums over this thread's 4 pixels ----
    const float mu0 = mu_s[p0 + 0], mu1 = mu_s[p0 + 1];
    const float mu2 = mu_s[p0 + 2], mu3 = mu_s[p0 + 3];
    const float r0 = rs_s[p0 + 0], r1 = rs_s[p0 + 1];
    const float r2 = rs_s[p0 + 2], r3 = rs_s[p0 + 3];
#pragma unroll
    for (int it = 0; it < 16; ++it) {
        unsigned c = (unsigned)it * 16u + cg;
        float w = r0 * (v[it].x - mu0) + r1 * (v[it].y - mu1)
                + r2 * (v[it].z - mu2) + r3 * (v[it].w - mu3);
        ps[c * PS_PITCH + pg] = w;
    }
    __syncthreads();

    // ---- Stage 3b: per-channel patch mean (256 threads = 256 channels) ----
    {
        float s = 0.f;
#pragma unroll
        for (int j = 0; j < 16; ++j) s += ps[t * PS_PITCH + j];
        pm_s[t] = g_c * s * (1.0f / 64.0f) + b_c;
    }
    __syncthreads();

    // ---- Stage 4a: h = silu(w1 @ pm), w1 is [32][256] row-major ----
    {
        const int r = t >> 3;                // output row 0..31
        const int k = t & 7;                 // 8-way split of the dot
        const float4* wrow = reinterpret_cast<const float4*>(w1 + r * C_DIM + k * 32);
        const float* pmk = &pm_s[k * 32];
        float s = 0.f;
#pragma unroll
        for (int j = 0; j < 8; ++j) {
            float4 wv = wrow[j];
            s += wv.x * pmk[j * 4 + 0] + wv.y * pmk[j * 4 + 1]
               + wv.z * pmk[j * 4 + 2] + wv.w * pmk[j * 4 + 3];
        }
        s += __shfl_down(s, 4, 8);
        s += __shfl_down(s, 2, 8);
        s += __shfl_down(s, 1, 8);
        if (k == 0) {
            float sig = 1.0f / (1.0f + __expf(-s));
            h_s[r] = s * sig;                // silu
        }
    }
    __syncthreads();

    // ---- Stage 4b: gate = sigmoid(w2 @ h); fold gamma/beta into gate ----
    {
        const float4* wrow = reinterpret_cast<const float4*>(w2 + t * R_DIM);
        float s = 0.f;
#pragma unroll
        for (int j = 0; j < 8; ++j) {
            float4 wv = wrow[j];
            s += wv.x * h_s[j * 4 + 0] + wv.y * h_s[j * 4 + 1]
               + wv.z * h_s[j * 4 + 2] + wv.w * h_s[j * 4 + 3];
        }
        float gate = 1.0f / (1.0f + __expf(-s));
        A_s[t] = g_c * gate;
        B_s[t] = b_c * gate;
    }
    __syncthreads();

    // ---- Stage 5: out = (gamma*rstd*(x-mu) + beta) * gate, from registers ----
#pragma unroll
    for (int it = 0; it < 16; ++it) {
        unsigned c = (unsigned)it * 16u + cg;
        float a  = A_s[c];                   // 16 lanes same addr -> broadcast
        float bb = B_s[c];
        float4 o;
        o.x = a * r0 * (v[it].x - mu0) + bb;
        o.y = a * r1 * (v[it].y - mu1) + bb;
        o.z = a * r2 * (v[it].z - mu2) + bb;
        o.w = a * r3 * (v[it].w - mu3) + bb;
        *reinterpret_cast<float4*>(out + rowoff + c * (HWDIM * HWDIM)) = o;
    }
}

extern "C" void kernel_launch(void* const* d_in, const int* in_sizes, int n_in,
                              void* d_out, int out_size, void* d_ws, size_t ws_size,
                              hipStream_t stream) {
    const float* x     = (const float*)d_in[0];
    const float* gamma = (const float*)d_in[1];
    const float* beta  = (const float*)d_in[2];
    const float* w1    = (const float*)d_in[3];
    const float* w2    = (const float*)d_in[4];
    float* out = (float*)d_out;

    const int B = in_sizes[0] / (C_DIM * HWDIM * HWDIM);                 // 8
    const int nwg = B * (HWDIM / PATCH_SZ) * (HWDIM / PATCH_SZ);         // 8192

    lpa_fused_kernel<<<nwg, 256, 0, stream>>>(x, gamma, beta, w1, w2, out, nwg);
}

// Round 3
// 258.538 us; speedup vs baseline: 1.5892x; 1.5892x over previous
//
#include <hip/hip_runtime.h>
#include <math.h>

#define C_DIM 256
#define HWDIM 256
#define CH_STRIDE (HWDIM * HWDIM)      // 65536 floats between channels
#define R_DIM 32

// Block = 4 horizontally-adjacent 8x8 patches: region 8 rows x 32 cols x 256 ch.
// 1024 threads = 16 waves. Wave `wid` owns channels c = wid*16 + k, k=0..15.
// Lane l: row hh = l>>3, float4-col wq = l&7  -> one wave-instr = one channel's
// full 8x32 tile = 8 dense 128B lines. Thread holds 16 float4 in VGPRs.
__global__ __launch_bounds__(1024, 4)
void lpa_fused_kernel(const float* __restrict__ x,
                      const float* __restrict__ gamma,
                      const float* __restrict__ beta,
                      const float* __restrict__ w1,
                      const float* __restrict__ w2,
                      float* __restrict__ out)
{
    __shared__ float sp[16 * 256];     // per-wave partial sums  [wid][pixel]
    __shared__ float sq[16 * 256];     // per-wave partial sumsq [wid][pixel]
    __shared__ float mu_s[256];
    __shared__ float rs_s[256];
    __shared__ float gs[C_DIM];
    __shared__ float bs[C_DIM];
    __shared__ float pm_s[4 * C_DIM];  // [patch][c]
    __shared__ float h_s[4 * R_DIM];   // [patch][r]
    __shared__ float A_s[4 * C_DIM];   // gamma*gate
    __shared__ float B_s[4 * C_DIM];   // beta*gate

    const int t    = threadIdx.x;
    const int wid  = t >> 6;
    const int lane = t & 63;
    const int hh   = lane >> 3;        // row in region 0..7
    const int wq   = lane & 7;         // float4 col 0..7 (w = wq*4)
    const int pat  = wq >> 1;          // patch 0..3 within the group

    const int bid = blockIdx.x;
    const int b   = bid >> 8;          // 256 groups per image (32 gh x 8 gw)
    const int ij  = bid & 255;
    const unsigned H0 = (unsigned)(ij >> 3) * 8u;
    const unsigned W0 = (unsigned)(ij & 7) * 32u;
    const unsigned baseb  = (unsigned)b * (C_DIM * CH_STRIDE);
    const unsigned rowoff = baseb + (H0 + hh) * HWDIM + W0 + (unsigned)wq * 4u;

    if (t < C_DIM) { gs[t] = gamma[t]; bs[t] = beta[t]; }

    const float* xb = x + rowoff + (unsigned)wid * 16u * CH_STRIDE;

    // ---- Stage 1: load 16 channel-tiles into regs + per-pixel partial stats ----
    float4 v[16];
    float s0 = 0.f, s1 = 0.f, s2 = 0.f, s3 = 0.f;
    float q0 = 0.f, q1 = 0.f, q2 = 0.f, q3 = 0.f;
#pragma unroll
    for (int k = 0; k < 16; ++k) {
        v[k] = *reinterpret_cast<const float4*>(xb + (unsigned)k * CH_STRIDE);
        s0 += v[k].x; q0 += v[k].x * v[k].x;
        s1 += v[k].y; q1 += v[k].y * v[k].y;
        s2 += v[k].z; q2 += v[k].z * v[k].z;
        s3 += v[k].w; q3 += v[k].w * v[k].w;
    }
    const int p0 = hh * 32 + wq * 4;   // this thread's first pixel (0..255)
    *reinterpret_cast<float4*>(&sp[wid * 256 + p0]) = make_float4(s0, s1, s2, s3);
    *reinterpret_cast<float4*>(&sq[wid * 256 + p0]) = make_float4(q0, q1, q2, q3);
    __syncthreads();

    // ---- Stage 2: finalize per-pixel LN stats (256 threads, one per pixel) ----
    if (t < 256) {
        float s = 0.f, q = 0.f;
#pragma unroll
        for (int w = 0; w < 16; ++w) {
            s += sp[w * 256 + t];
            q += sq[w * 256 + t];
        }
        float mu  = s * (1.0f / 256.0f);
        float var = q * (1.0f / 256.0f) - mu * mu;
        mu_s[t] = mu;
        rs_s[t] = rsqrtf(var + 1e-5f);
    }
    __syncthreads();

    // ---- Stage 3: per-(patch, channel) mean of normalized values ----
    const float mu0 = mu_s[p0 + 0], mu1 = mu_s[p0 + 1];
    const float mu2 = mu_s[p0 + 2], mu3 = mu_s[p0 + 3];
    const float r0 = rs_s[p0 + 0], r1 = rs_s[p0 + 1];
    const float r2 = rs_s[p0 + 2], r3 = rs_s[p0 + 3];
#pragma unroll
    for (int k = 0; k < 16; ++k) {
        int c = wid * 16 + k;
        float wsum = r0 * (v[k].x - mu0) + r1 * (v[k].y - mu1)
                   + r2 * (v[k].z - mu2) + r3 * (v[k].w - mu3);
        // reduce over lane bits 0,3,4,5 (pixels within one patch); bits 1,2 = patch
        wsum += __shfl_xor(wsum, 1);
        wsum += __shfl_xor(wsum, 8);
        wsum += __shfl_xor(wsum, 16);
        wsum += __shfl_xor(wsum, 32);
        if ((lane & 57) == 0) {        // lanes 0,2,4,6 -> patches 0..3
            pm_s[pat * C_DIM + c] = gs[c] * wsum * (1.0f / 64.0f) + bs[c];
        }
    }
    __syncthreads();

    // ---- Stage 4a: h = silu(w1 @ pm) for 4 patches; w1 [32][256] row-major ----
    {
        const int pat4 = t >> 8;       // patch 0..3 (constant per wave)
        const int r    = (t >> 3) & 31;
        const int k8   = t & 7;        // 8-way split of the dot
        const float4* wrow = reinterpret_cast<const float4*>(w1 + r * C_DIM + k8 * 32);
        const float* pmk = &pm_s[pat4 * C_DIM + k8 * 32];
        float s = 0.f;
#pragma unroll
        for (int j = 0; j < 8; ++j) {
            float4 wv = wrow[j];
            float4 pv = *reinterpret_cast<const float4*>(pmk + j * 4);
            s += wv.x * pv.x + wv.y * pv.y + wv.z * pv.z + wv.w * pv.w;
        }
        s += __shfl_down(s, 4, 8);
        s += __shfl_down(s, 2, 8);
        s += __shfl_down(s, 1, 8);
        if (k8 == 0) {
            float sig = 1.0f / (1.0f + __expf(-s));
            h_s[pat4 * R_DIM + r] = s * sig;
        }
    }
    __syncthreads();

    // ---- Stage 4b: gate = sigmoid(w2 @ h); fold gamma/beta; w2 [256][32] ----
    {
        const int pat4 = t >> 8;
        const int c4   = t & 255;
        const float4* wrow = reinterpret_cast<const float4*>(w2 + c4 * R_DIM);
        const float* hk = &h_s[pat4 * R_DIM];
        float s = 0.f;
#pragma unroll
        for (int j = 0; j < 8; ++j) {
            float4 wv = wrow[j];
            s += wv.x * hk[j * 4 + 0] + wv.y * hk[j * 4 + 1]
               + wv.z * hk[j * 4 + 2] + wv.w * hk[j * 4 + 3];
        }
        float gate = 1.0f / (1.0f + __expf(-s));
        A_s[pat4 * C_DIM + c4] = gs[c4] * gate;
        B_s[pat4 * C_DIM + c4] = bs[c4] * gate;
    }
    __syncthreads();

    // ---- Stage 5: out = (gamma*rstd*(x-mu) + beta) * gate, dense stores ----
    float* ob = out + rowoff + (unsigned)wid * 16u * CH_STRIDE;
#pragma unroll
    for (int k = 0; k < 16; ++k) {
        int c = wid * 16 + k;
        float a  = A_s[pat * C_DIM + c];
        float bb = B_s[pat * C_DIM + c];
        float4 o;
        o.x = a * r0 * (v[k].x - mu0) + bb;
        o.y = a * r1 * (v[k].y - mu1) + bb;
        o.z = a * r2 * (v[k].z - mu2) + bb;
        o.w = a * r3 * (v[k].w - mu3) + bb;
        *reinterpret_cast<float4*>(ob + (unsigned)k * CH_STRIDE) = o;
    }
}

extern "C" void kernel_launch(void* const* d_in, const int* in_sizes, int n_in,
                              void* d_out, int out_size, void* d_ws, size_t ws_size,
                              hipStream_t stream) {
    const float* x     = (const float*)d_in[0];
    const float* gamma = (const float*)d_in[1];
    const float* beta  = (const float*)d_in[2];
    const float* w1    = (const float*)d_in[3];
    const float* w2    = (const float*)d_in[4];
    float* out = (float*)d_out;

    const int B = in_sizes[0] / (C_DIM * HWDIM * HWDIM);   // 8
    const int nwg = B * 256;                               // 2048 groups of 4 patches

    lpa_fused_kernel<<<nwg, 1024, 0, stream>>>(x, gamma, beta, w1, w2, out);
}